// Round 10
// baseline (354.325 us; speedup 1.0000x reference)
//
#include <hip/hip_runtime.h>
#include <hip/hip_fp16.h>
#include <math.h>

#define F_IN 12
#define NHID 64
#define HGCN 61
#define EMB_OUT 54
#define SCAN_CH 1024
#define PART_R 8192           // edge records per partition block (LDS-staged)
#define DEG_SCALE 32768.0f    // 2^15 fixed-point for weighted degree
#define NRM_SCALE 32768.0f    // 15-bit fixed-point for norm (norm <= 0.708, never clamps)

typedef unsigned int uint;
typedef unsigned short ushort;
typedef unsigned char uchar;

__device__ __forceinline__ float gelu_exact(float v) {
    return 0.5f * v * (1.0f + erff(v * 0.70710678118654752440f));
}

__device__ __forceinline__ void atomic_add_f32(float* p, float v) {
    unsafeAtomicAdd(p, v);   // hardware global_atomic_add_f32
}

// ---- prep: weight table sp[4] = {1.0 (no mask), softmax0, softmax1, softmax2};
//      spq fixed-point; fold W_emb/b_emb into W_gcn -> W_eff(12x64), b_eff
__global__ void prep_kernel(const float* __restrict__ msg_w,
                            const float* __restrict__ W_emb,
                            const float* __restrict__ b_emb,
                            const float* __restrict__ W_gcn,
                            float* __restrict__ sp, uint* __restrict__ spq,
                            float* __restrict__ W_eff, float* __restrict__ b_eff) {
    __shared__ float ssp[4];
    int t = threadIdx.x;
    if (t == 0) {
        float m = fmaxf(msg_w[0], fmaxf(msg_w[1], msg_w[2]));
        float e0 = expf(msg_w[0] - m), e1 = expf(msg_w[1] - m), e2 = expf(msg_w[2] - m);
        float s = e0 + e1 + e2;
        ssp[0] = 1.0f; ssp[1] = e0 / s; ssp[2] = e1 / s; ssp[3] = e2 / s;
        sp[0] = ssp[0]; sp[1] = ssp[1]; sp[2] = ssp[2]; sp[3] = ssp[3];
    }
    __syncthreads();
    if (t < 4) spq[t] = __float2uint_rn(ssp[t] * DEG_SCALE);
    if (t < HGCN) {
        float be = 0.f, w0 = 0.f, w1 = 0.f;
        for (int k = 0; k < EMB_OUT; ++k) {
            float g = W_gcn[k * HGCN + t];
            be += b_emb[k] * g;
            w0 += W_emb[k] * g;
            w1 += W_emb[EMB_OUT + k] * g;
        }
        b_eff[t] = be;
        W_eff[0 * 64 + t] = w0;
        W_eff[1 * 64 + t] = w1;
        for (int f = 2; f < F_IN; ++f)
            W_eff[f * 64 + t] = W_gcn[(EMB_OUT + f - 2) * HGCN + t];
    }
}

// masks write weight-class bytes; later kernel wins (dispatch order) == torch indexed assign.
__global__ void set_mask_u8(uchar* __restrict__ wclass, const int* __restrict__ mask,
                            uchar v, int n) {
    int i = blockIdx.x * blockDim.x + threadIdx.x;
    if (i < n) wclass[mask[i]] = v;
}

// K1: per-block histogram of destination buckets (col>>8) -> H[bucket*NBLK + blk].
// Also zero-inits wclass (runs BEFORE set_mask kernels).
__global__ __launch_bounds__(256) void k1_hist(const int* __restrict__ ei,
                                               uint* __restrict__ H,
                                               uchar* __restrict__ wclass,
                                               int E, int NB, int NBLK) {
    __shared__ uint hist[512];
    int blk = blockIdx.x, t = threadIdx.x;
    hist[t] = 0; hist[t + 256] = 0;
    __syncthreads();
    int lo = blk * PART_R, hi = min(lo + PART_R, E);
    for (int i = lo + t; i < hi; i += 256) {
        wclass[i] = 0;
        atomicAdd(&hist[((uint)ei[E + i]) >> 8], 1u);
    }
    __syncthreads();
    for (int b = t; b < NB; b += 256) H[(size_t)b * NBLK + blk] = hist[b];
}

// ---- exclusive scan (2 kernels)
__global__ void scan_partial_kernel(const int* __restrict__ cnt, int* __restrict__ startv,
                                    int* __restrict__ bsum, int n) {
    __shared__ int s[256];
    int t = threadIdx.x;
    int base = blockIdx.x * SCAN_CH + t * 4;
    int v0 = (base + 0 < n) ? cnt[base + 0] : 0;
    int v1 = (base + 1 < n) ? cnt[base + 1] : 0;
    int v2 = (base + 2 < n) ? cnt[base + 2] : 0;
    int v3 = (base + 3 < n) ? cnt[base + 3] : 0;
    int loc = v0 + v1 + v2 + v3;
    s[t] = loc;
    __syncthreads();
    for (int off = 1; off < 256; off <<= 1) {
        int u = (t >= off) ? s[t - off] : 0;
        __syncthreads();
        s[t] += u;
        __syncthreads();
    }
    int ex = s[t] - loc;
    if (t == 255) bsum[blockIdx.x] = s[255];   // raw block sum
    if (base + 0 < n) startv[base + 0] = ex;
    if (base + 1 < n) startv[base + 1] = ex + v0;
    if (base + 2 < n) startv[base + 2] = ex + v0 + v1;
    if (base + 3 < n) startv[base + 3] = ex + v0 + v1 + v2;
}

// scan_add with inline bsum prefix: block covers 256 indices, i/SCAN_CH constant per block.
__global__ void scan_add_kernel(int* __restrict__ startv, const int* __restrict__ bsum, int n) {
    __shared__ int soff;
    int b = blockIdx.x;
    if (threadIdx.x == 0) {
        int q = (b * 256) / SCAN_CH;
        int acc = 0;
        for (int j = 0; j < q; ++j) acc += bsum[j];
        soff = acc;
    }
    __syncthreads();
    int i = b * 256 + threadIdx.x;
    if (i < n) startv[i] += soff;
}

// K3: LDS-staged partition to BUCKET granularity.
// Pack rec = row<<10 | (col&255)<<2 | wclass; write bucket-grouped.
__global__ __launch_bounds__(256) void k3_partition(
        const int* __restrict__ ei, const uchar* __restrict__ wclass,
        const uint* __restrict__ Hs, uint* __restrict__ recSorted,
        int E, int NB, int NBLK) {
    __shared__ uint recs[PART_R];
    __shared__ ushort sbkt[PART_R];
    __shared__ uint hist[512];
    __shared__ uint scanA[512];
    __shared__ uint scanB[512];
    __shared__ int  gbase[512];
    __shared__ uint cursor[512];
    int blk = blockIdx.x, t = threadIdx.x;
    int lo = blk * PART_R, hi = min(lo + PART_R, E);
    int cntTot = hi - lo;
    hist[t] = 0; hist[t + 256] = 0;
    __syncthreads();
    for (int i = lo + t; i < hi; i += 256)
        atomicAdd(&hist[((uint)ei[E + i]) >> 8], 1u);
    __syncthreads();
    uint* src = scanA; uint* dst = scanB;
    src[t] = hist[t]; src[t + 256] = hist[t + 256];
    __syncthreads();
    for (int off = 1; off < 512; off <<= 1) {
        dst[t]       = src[t]       + ((t >= off)       ? src[t - off]       : 0u);
        dst[t + 256] = src[t + 256] + ((t + 256 >= off) ? src[t + 256 - off] : 0u);
        __syncthreads();
        uint* tmp = src; src = dst; dst = tmp;
    }
    uint l0 = (t == 0) ? 0u : src[t - 1];
    uint l1 = src[t + 255];
    cursor[t] = l0; cursor[t + 256] = l1;
    if (t < NB)       gbase[t]       = (int)Hs[(size_t)t * NBLK + blk]         - (int)l0;
    if (t + 256 < NB) gbase[t + 256] = (int)Hs[(size_t)(t + 256) * NBLK + blk] - (int)l1;
    __syncthreads();
    for (int i = lo + t; i < hi; i += 256) {
        uint row = (uint)ei[i];
        uint col = (uint)ei[E + i];
        uint b = col >> 8;
        uint rec = (row << 10) | ((col & 255u) << 2) | (uint)wclass[i];
        uint slot = atomicAdd(&cursor[b], 1u);
        recs[slot] = rec;
        sbkt[slot] = (ushort)b;
    }
    __syncthreads();
    for (int s = t; s < cntTot; s += 256)
        recSorted[gbase[sbkt[s]] + s] = recs[s];
}

// K2: per-bucket node stats: cnt, startv (node-exact global CSR offset), dis = rsqrt(deg+1)
__global__ __launch_bounds__(256) void k2_stats(
        const uint* __restrict__ recSorted, const uint* __restrict__ Hs,
        const uint* __restrict__ spq,
        uint* __restrict__ cnt, uint* __restrict__ startv, float* __restrict__ dis,
        int E, int NB, int NBLK, int n_nodes) {
    __shared__ uint hcnt[256], hdeg[256], sA[256], sB[256];
    __shared__ uint sq[4];
    int b = blockIdx.x, t = threadIdx.x;
    hcnt[t] = 0; hdeg[t] = 0;
    if (t < 4) sq[t] = spq[t];
    __syncthreads();
    uint lo = Hs[(size_t)b * NBLK];
    uint hi = (b + 1 < NB) ? Hs[(size_t)(b + 1) * NBLK] : (uint)E;
    for (uint i = lo + t; i < hi; i += 256) {
        uint r = recSorted[i];
        atomicAdd(&hcnt[(r >> 2) & 255u], 1u);
        atomicAdd(&hdeg[(r >> 2) & 255u], sq[r & 3u]);
    }
    __syncthreads();
    uint* src = sA; uint* dst = sB;
    src[t] = hcnt[t];
    __syncthreads();
    for (int off = 1; off < 256; off <<= 1) {
        dst[t] = src[t] + ((t >= off) ? src[t - off] : 0u);
        __syncthreads();
        uint* tmp = src; src = dst; dst = tmp;
    }
    uint excl = (t == 0) ? 0u : src[t - 1];
    int node = (b << 8) + t;
    if (node < n_nodes) {
        cnt[node] = hcnt[t];
        startv[node] = lo + excl;
        float deg = (float)hdeg[t] * (1.0f / DEG_SCALE) + 1.0f;
        dis[node] = rsqrtf(deg);
    }
}

// K4: second-level partition + payload fill. payload = row<<15 | round(norm*32768)
__global__ __launch_bounds__(256) void k4_payload(
        const uint* __restrict__ recSorted, const uint* __restrict__ Hs,
        const float* __restrict__ sp, const float* __restrict__ dis,
        const uint* __restrict__ startv,
        uint* __restrict__ payload, int E, int NB, int NBLK, int n_nodes) {
    __shared__ float disl[256];
    __shared__ uint cur[256];
    __shared__ float spl[4];
    int b = blockIdx.x, t = threadIdx.x;
    int node = (b << 8) + t;
    disl[t] = (node < n_nodes) ? dis[node] : 0.0f;
    cur[t]  = (node < n_nodes) ? startv[node] : 0u;
    if (t < 4) spl[t] = sp[t];
    __syncthreads();
    uint lo = Hs[(size_t)b * NBLK];
    uint hi = (b + 1 < NB) ? Hs[(size_t)(b + 1) * NBLK] : (uint)E;
    for (uint i = lo + t; i < hi; i += 256) {
        uint r = recSorted[i];
        uint row = r >> 10;
        uint c = (r >> 2) & 255u;
        float nrm = dis[row] * spl[r & 3u] * disl[c];
        uint pos = atomicAdd(&cur[c], 1u);
        payload[pos] = (row << 15) | __float2uint_rn(nrm * NRM_SCALE);
    }
}

// h2 = x @ W_eff + b_eff, stored fp16 (stride-64 padded, zeros at d>=61).
// First blocks also zero-init pooled (runs before gather).
__global__ void h2_kernel(const float* __restrict__ x, const float* __restrict__ W_eff,
                          const float* __restrict__ b_eff,
                          __half* __restrict__ h2, float* __restrict__ pooled, int g64,
                          int n_nodes) {
    int gid = blockIdx.x * 256 + threadIdx.x;
    if (gid < g64) pooled[gid] = 0.0f;
    int node = blockIdx.x * 4 + (threadIdx.x >> 6);
    int d = threadIdx.x & 63;
    if (node >= n_nodes) return;
    float v = 0.f;
    if (d < HGCN) {
        v = b_eff[d];
#pragma unroll
        for (int f = 0; f < F_IN; ++f)
            v += x[node * F_IN + f] * W_eff[f * 64 + d];
    }
    h2[node * 64 + d] = __float2half(v);
}

// gather + gelu + pool. 4 edges/wave per load inst: group g4 = lane>>4 handles edge 4k+g4;
// lane owns a dim QUAD (8B = 4 halfs) -> 16 lanes cover a 128B h2 row. 8-deep unroll = 32
// edges in flight. Out-of-range shfl sources carry p=0 (row 0, w=0 -> harmless).
__global__ void gather_pool_kernel(const uint* __restrict__ payload,
                                   const uint* __restrict__ startv, const uint* __restrict__ cnt,
                                   const float* __restrict__ dis,
                                   const uint2* __restrict__ h2q,
                                   const float* __restrict__ b_gcn, const int* __restrict__ batch,
                                   float* __restrict__ pooled, int n_nodes) {
    int node = blockIdx.x * 4 + (threadIdx.x >> 6);
    int lane = threadIdx.x & 63;
    int g4  = lane >> 4;        // edge offset within quad
    int s16 = lane & 15;        // dim-quad index: dims 4*s16 .. 4*s16+3
    if (node >= n_nodes) return;
    int s = (int)startv[node];
    int m = (int)cnt[node];
    const float inv = 1.0f / NRM_SCALE;
    float a0 = 0.f, a1 = 0.f, a2 = 0.f, a3 = 0.f;
    if (g4 == 0) {              // self-loop term only in group 0
        float di = dis[node];
        uint2 q = h2q[node * 16 + s16];
        float2 lo = __half22float2(*(const __half2*)&q.x);
        float2 hi = __half22float2(*(const __half2*)&q.y);
        float d2 = di * di;
        a0 = d2 * lo.x; a1 = d2 * lo.y; a2 = d2 * hi.x; a3 = d2 * hi.y;
    }
    for (int j0 = 0; j0 < m; j0 += 64) {
        uint p = 0;
        if (j0 + lane < m) p = payload[s + j0 + lane];  // coalesced 256B chunk load
        int lim = min(64, m - j0);
        int nq = (lim + 3) >> 2;
        int k = 0;
        for (; k + 8 <= nq; k += 8) {                   // 8 load insts = 32 edges in flight
            uint p0 = __shfl(p, 4 * (k + 0) + g4);
            uint p1 = __shfl(p, 4 * (k + 1) + g4);
            uint p2 = __shfl(p, 4 * (k + 2) + g4);
            uint p3 = __shfl(p, 4 * (k + 3) + g4);
            uint p4 = __shfl(p, 4 * (k + 4) + g4);
            uint p5 = __shfl(p, 4 * (k + 5) + g4);
            uint p6 = __shfl(p, 4 * (k + 6) + g4);
            uint p7 = __shfl(p, 4 * (k + 7) + g4);
            uint2 q0 = h2q[(p0 >> 15) * 16 + s16];
            uint2 q1 = h2q[(p1 >> 15) * 16 + s16];
            uint2 q2 = h2q[(p2 >> 15) * 16 + s16];
            uint2 q3 = h2q[(p3 >> 15) * 16 + s16];
            uint2 q4 = h2q[(p4 >> 15) * 16 + s16];
            uint2 q5 = h2q[(p5 >> 15) * 16 + s16];
            uint2 q6 = h2q[(p6 >> 15) * 16 + s16];
            uint2 q7 = h2q[(p7 >> 15) * 16 + s16];
#define ACC(pi, qi)                                                        \
            {                                                              \
                float w = (float)(pi & 32767u) * inv;                      \
                float2 lo = __half22float2(*(const __half2*)&qi.x);        \
                float2 hi = __half22float2(*(const __half2*)&qi.y);        \
                a0 += w * lo.x; a1 += w * lo.y;                            \
                a2 += w * hi.x; a3 += w * hi.y;                            \
            }
            ACC(p0, q0) ACC(p1, q1) ACC(p2, q2) ACC(p3, q3)
            ACC(p4, q4) ACC(p5, q5) ACC(p6, q6) ACC(p7, q7)
        }
        for (; k < nq; ++k) {
            uint pk = __shfl(p, 4 * k + g4);
            uint2 qk = h2q[(pk >> 15) * 16 + s16];
            ACC(pk, qk)
        }
#undef ACC
    }
    // combine the 4 edge groups: lanes s16, s16+16, s16+32, s16+48 hold partials of same dims
    a0 += __shfl_xor(a0, 16); a0 += __shfl_xor(a0, 32);
    a1 += __shfl_xor(a1, 16); a1 += __shfl_xor(a1, 32);
    a2 += __shfl_xor(a2, 16); a2 += __shfl_xor(a2, 32);
    a3 += __shfl_xor(a3, 16); a3 += __shfl_xor(a3, 32);
    if (lane < 16) {
        int d = 4 * lane;
        float* pg = &pooled[batch[node] * 64];
        if (d + 0 < HGCN) atomic_add_f32(pg + d + 0, gelu_exact(a0 + b_gcn[d + 0]));
        if (d + 1 < HGCN) atomic_add_f32(pg + d + 1, gelu_exact(a1 + b_gcn[d + 1]));
        if (d + 2 < HGCN) atomic_add_f32(pg + d + 2, gelu_exact(a2 + b_gcn[d + 2]));
        if (d + 3 < HGCN) atomic_add_f32(pg + d + 3, gelu_exact(a3 + b_gcn[d + 3]));
    }
}

// per-graph head
__global__ void final_kernel(const float* __restrict__ pooled,
                             const float* __restrict__ fn_avg,
                             const float* __restrict__ inf_rate,
                             const float* __restrict__ W_fn1, const float* __restrict__ b_fn1,
                             const float* __restrict__ W_fn2, const float* __restrict__ b_fn2,
                             const float* __restrict__ W_bb1, const float* __restrict__ b_bb1,
                             const float* __restrict__ W_out, const float* __restrict__ b_out,
                             float* __restrict__ logits) {
    __shared__ float z[64];
    __shared__ float t1[16];
    int g = blockIdx.x;
    int t = threadIdx.x;
    if (t < HGCN) z[t] = pooled[g * 64 + t];
    float e0 = fn_avg[g * 2], e1 = fn_avg[g * 2 + 1], e2 = inf_rate[g];
    if (t < 16) {
        float a = e0 * W_fn1[t] + e1 * W_fn1[16 + t] + e2 * W_fn1[32 + t] + b_fn1[t];
        t1[t] = gelu_exact(a);
    }
    __syncthreads();
    if (t < 3) {
        float a = b_fn2[t];
#pragma unroll
        for (int k = 0; k < 16; ++k) a += t1[k] * W_fn2[k * 3 + t];
        z[HGCN + t] = a;
    }
    __syncthreads();
    float acc = b_bb1[t];
#pragma unroll 8
    for (int k = 0; k < 64; ++k) acc += z[k] * W_bb1[k * 64 + t];
    float p = gelu_exact(acc) * W_out[t];
#pragma unroll
    for (int off = 32; off > 0; off >>= 1) p += __shfl_down(p, off);
    if (t == 0) logits[g] = p + b_out[0];
}

extern "C" void kernel_launch(void* const* d_in, const int* in_sizes, int n_in,
                              void* d_out, int out_size, void* d_ws, size_t ws_size,
                              hipStream_t stream) {
    const float* x        = (const float*)d_in[0];
    const int*   ei       = (const int*)d_in[1];
    const int*   batch    = (const int*)d_in[2];
    const int*   known    = (const int*)d_in[3];
    const int*   unk      = (const int*)d_in[4];
    const int*   obs      = (const int*)d_in[5];
    const float* fn_avg   = (const float*)d_in[6];
    const float* inf_rate = (const float*)d_in[7];
    const float* msg_w    = (const float*)d_in[8];
    const float* W_emb    = (const float*)d_in[9];
    const float* b_emb    = (const float*)d_in[10];
    const float* W_gcn    = (const float*)d_in[11];
    const float* b_gcn    = (const float*)d_in[12];
    const float* W_fn1    = (const float*)d_in[13];
    const float* b_fn1    = (const float*)d_in[14];
    const float* W_fn2    = (const float*)d_in[15];
    const float* b_fn2    = (const float*)d_in[16];
    const float* W_bb1    = (const float*)d_in[17];
    const float* b_bb1    = (const float*)d_in[18];
    const float* W_out    = (const float*)d_in[19];
    const float* b_out    = (const float*)d_in[20];
    float* logits = (float*)d_out;

    const int n_nodes = in_sizes[0] / F_IN;
    const int E       = in_sizes[1] / 2;
    const int nk = in_sizes[3], nu = in_sizes[4], no = in_sizes[5];
    const int G = in_sizes[6] / 2;

    const int NB   = (n_nodes + 255) >> 8;
    const int NBLK = (E + PART_R - 1) / PART_R;
    const int L    = NB * NBLK;
    const int nbL  = (L + SCAN_CH - 1) / SCAN_CH;

    char* ws = (char*)d_ws;
    size_t off = 0;
    auto alloc = [&](size_t bytes) -> void* {
        void* p = ws + off;
        off += (bytes + 255) & ~size_t(255);
        return p;
    };
    uchar*  wclass    = (uchar*)alloc(sizeof(uchar) * (size_t)E);
    uint*   recSorted = (uint*)alloc(sizeof(uint) * (size_t)E);
    uint*   H         = (uint*)alloc(sizeof(uint) * (size_t)L);
    uint*   Hs        = (uint*)alloc(sizeof(uint) * (size_t)L);
    int*    bsum      = (int*)alloc(sizeof(int) * (size_t)(nbL + 1));
    __half* h2        = (__half*)alloc(sizeof(__half) * (size_t)n_nodes * 64);
    uint*   payload   = (uint*)alloc(sizeof(uint) * (size_t)E);
    uint*   cntv      = (uint*)alloc(sizeof(uint) * (size_t)n_nodes);
    uint*   startv    = (uint*)alloc(sizeof(uint) * (size_t)n_nodes);
    float*  dis       = (float*)alloc(sizeof(float) * (size_t)n_nodes);
    float*  pooled    = (float*)alloc(sizeof(float) * (size_t)G * 64);
    float*  W_eff     = (float*)alloc(sizeof(float) * F_IN * 64);
    float*  b_eff     = (float*)alloc(sizeof(float) * 64);
    float*  sp        = (float*)alloc(sizeof(float) * 4);
    uint*   spq       = (uint*)alloc(sizeof(uint) * 4);

    prep_kernel<<<1, 64, 0, stream>>>(msg_w, W_emb, b_emb, W_gcn, sp, spq, W_eff, b_eff);
    k1_hist<<<NBLK, 256, 0, stream>>>(ei, H, wclass, E, NB, NBLK);   // also zeroes wclass
    set_mask_u8<<<(nk + 255) / 256, 256, 0, stream>>>(wclass, known, 1, nk);
    set_mask_u8<<<(nu + 255) / 256, 256, 0, stream>>>(wclass, unk, 2, nu);
    set_mask_u8<<<(no + 255) / 256, 256, 0, stream>>>(wclass, obs, 3, no);
    scan_partial_kernel<<<nbL, 256, 0, stream>>>((const int*)H, (int*)Hs, bsum, L);
    scan_add_kernel<<<(L + 255) / 256, 256, 0, stream>>>((int*)Hs, bsum, L);
    k3_partition<<<NBLK, 256, 0, stream>>>(ei, wclass, Hs, recSorted, E, NB, NBLK);
    k2_stats<<<NB, 256, 0, stream>>>(recSorted, Hs, spq, cntv, startv, dis, E, NB, NBLK, n_nodes);
    h2_kernel<<<(n_nodes + 3) / 4, 256, 0, stream>>>(x, W_eff, b_eff, h2, pooled, G * 64, n_nodes);
    k4_payload<<<NB, 256, 0, stream>>>(recSorted, Hs, sp, dis, startv, payload, E, NB, NBLK, n_nodes);
    gather_pool_kernel<<<(n_nodes + 3) / 4, 256, 0, stream>>>(payload, startv, cntv, dis,
                                                              (const uint2*)h2, b_gcn, batch,
                                                              pooled, n_nodes);
    final_kernel<<<G, 64, 0, stream>>>(pooled, fn_avg, inf_rate, W_fn1, b_fn1,
                                       W_fn2, b_fn2, W_bb1, b_bb1, W_out, b_out, logits);
}

// Round 11
// 245.332 us; speedup vs baseline: 1.4443x; 1.4443x over previous
//
#include <hip/hip_runtime.h>
#include <hip/hip_fp16.h>
#include <math.h>

#define F_IN 12
#define NHID 64
#define HGCN 61
#define EMB_OUT 54
#define SCAN_CH 1024
#define PART_R 8192           // edge records per partition block (LDS-staged)
#define DEG_SCALE 32768.0f    // 2^15 fixed-point for weighted degree
#define NRM_SCALE 32768.0f    // 15-bit fixed-point for norm (norm <= 0.708, never clamps)

typedef unsigned int uint;
typedef unsigned short ushort;
typedef unsigned char uchar;

__device__ __forceinline__ float gelu_exact(float v) {
    return 0.5f * v * (1.0f + erff(v * 0.70710678118654752440f));
}

__device__ __forceinline__ void atomic_add_f32(float* p, float v) {
    unsafeAtomicAdd(p, v);   // hardware global_atomic_add_f32
}

// ---- prep: weight table sp[4] = {1.0 (no mask), softmax0, softmax1, softmax2};
//      spq fixed-point; fold W_emb/b_emb into W_gcn -> W_eff(12x64), b_eff
__global__ void prep_kernel(const float* __restrict__ msg_w,
                            const float* __restrict__ W_emb,
                            const float* __restrict__ b_emb,
                            const float* __restrict__ W_gcn,
                            float* __restrict__ sp, uint* __restrict__ spq,
                            float* __restrict__ W_eff, float* __restrict__ b_eff) {
    __shared__ float ssp[4];
    int t = threadIdx.x;
    if (t == 0) {
        float m = fmaxf(msg_w[0], fmaxf(msg_w[1], msg_w[2]));
        float e0 = expf(msg_w[0] - m), e1 = expf(msg_w[1] - m), e2 = expf(msg_w[2] - m);
        float s = e0 + e1 + e2;
        ssp[0] = 1.0f; ssp[1] = e0 / s; ssp[2] = e1 / s; ssp[3] = e2 / s;
        sp[0] = ssp[0]; sp[1] = ssp[1]; sp[2] = ssp[2]; sp[3] = ssp[3];
    }
    __syncthreads();
    if (t < 4) spq[t] = __float2uint_rn(ssp[t] * DEG_SCALE);
    if (t < HGCN) {
        float be = 0.f, w0 = 0.f, w1 = 0.f;
        for (int k = 0; k < EMB_OUT; ++k) {
            float g = W_gcn[k * HGCN + t];
            be += b_emb[k] * g;
            w0 += W_emb[k] * g;
            w1 += W_emb[EMB_OUT + k] * g;
        }
        b_eff[t] = be;
        W_eff[0 * 64 + t] = w0;
        W_eff[1 * 64 + t] = w1;
        for (int f = 2; f < F_IN; ++f)
            W_eff[f * 64 + t] = W_gcn[(EMB_OUT + f - 2) * HGCN + t];
    }
}

// masks write weight-class bytes; later kernel wins (dispatch order) == torch indexed assign.
__global__ void set_mask_u8(uchar* __restrict__ wclass, const int* __restrict__ mask,
                            uchar v, int n) {
    int i = blockIdx.x * blockDim.x + threadIdx.x;
    if (i < n) wclass[mask[i]] = v;
}

// K1: per-block histogram of destination buckets (col>>8) -> H[bucket*NBLK + blk].
// Also zero-inits wclass (runs BEFORE set_mask kernels).
__global__ __launch_bounds__(256) void k1_hist(const int* __restrict__ ei,
                                               uint* __restrict__ H,
                                               uchar* __restrict__ wclass,
                                               int E, int NB, int NBLK) {
    __shared__ uint hist[512];
    int blk = blockIdx.x, t = threadIdx.x;
    hist[t] = 0; hist[t + 256] = 0;
    __syncthreads();
    int lo = blk * PART_R, hi = min(lo + PART_R, E);
    for (int i = lo + t; i < hi; i += 256) {
        wclass[i] = 0;
        atomicAdd(&hist[((uint)ei[E + i]) >> 8], 1u);
    }
    __syncthreads();
    for (int b = t; b < NB; b += 256) H[(size_t)b * NBLK + blk] = hist[b];
}

// ---- exclusive scan (2 kernels)
__global__ void scan_partial_kernel(const int* __restrict__ cnt, int* __restrict__ startv,
                                    int* __restrict__ bsum, int n) {
    __shared__ int s[256];
    int t = threadIdx.x;
    int base = blockIdx.x * SCAN_CH + t * 4;
    int v0 = (base + 0 < n) ? cnt[base + 0] : 0;
    int v1 = (base + 1 < n) ? cnt[base + 1] : 0;
    int v2 = (base + 2 < n) ? cnt[base + 2] : 0;
    int v3 = (base + 3 < n) ? cnt[base + 3] : 0;
    int loc = v0 + v1 + v2 + v3;
    s[t] = loc;
    __syncthreads();
    for (int off = 1; off < 256; off <<= 1) {
        int u = (t >= off) ? s[t - off] : 0;
        __syncthreads();
        s[t] += u;
        __syncthreads();
    }
    int ex = s[t] - loc;
    if (t == 255) bsum[blockIdx.x] = s[255];   // raw block sum
    if (base + 0 < n) startv[base + 0] = ex;
    if (base + 1 < n) startv[base + 1] = ex + v0;
    if (base + 2 < n) startv[base + 2] = ex + v0 + v1;
    if (base + 3 < n) startv[base + 3] = ex + v0 + v1 + v2;
}

// scan_add with inline bsum prefix: block covers 256 indices, i/SCAN_CH constant per block.
__global__ void scan_add_kernel(int* __restrict__ startv, const int* __restrict__ bsum, int n) {
    __shared__ int soff;
    int b = blockIdx.x;
    if (threadIdx.x == 0) {
        int q = (b * 256) / SCAN_CH;
        int acc = 0;
        for (int j = 0; j < q; ++j) acc += bsum[j];
        soff = acc;
    }
    __syncthreads();
    int i = b * 256 + threadIdx.x;
    if (i < n) startv[i] += soff;
}

// K3: LDS-staged partition to BUCKET granularity.
// Pack rec = row<<10 | (col&255)<<2 | wclass; write bucket-grouped.
__global__ __launch_bounds__(256) void k3_partition(
        const int* __restrict__ ei, const uchar* __restrict__ wclass,
        const uint* __restrict__ Hs, uint* __restrict__ recSorted,
        int E, int NB, int NBLK) {
    __shared__ uint recs[PART_R];
    __shared__ ushort sbkt[PART_R];
    __shared__ uint hist[512];
    __shared__ uint scanA[512];
    __shared__ uint scanB[512];
    __shared__ int  gbase[512];
    __shared__ uint cursor[512];
    int blk = blockIdx.x, t = threadIdx.x;
    int lo = blk * PART_R, hi = min(lo + PART_R, E);
    int cntTot = hi - lo;
    hist[t] = 0; hist[t + 256] = 0;
    __syncthreads();
    for (int i = lo + t; i < hi; i += 256)
        atomicAdd(&hist[((uint)ei[E + i]) >> 8], 1u);
    __syncthreads();
    uint* src = scanA; uint* dst = scanB;
    src[t] = hist[t]; src[t + 256] = hist[t + 256];
    __syncthreads();
    for (int off = 1; off < 512; off <<= 1) {
        dst[t]       = src[t]       + ((t >= off)       ? src[t - off]       : 0u);
        dst[t + 256] = src[t + 256] + ((t + 256 >= off) ? src[t + 256 - off] : 0u);
        __syncthreads();
        uint* tmp = src; src = dst; dst = tmp;
    }
    uint l0 = (t == 0) ? 0u : src[t - 1];
    uint l1 = src[t + 255];
    cursor[t] = l0; cursor[t + 256] = l1;
    if (t < NB)       gbase[t]       = (int)Hs[(size_t)t * NBLK + blk]         - (int)l0;
    if (t + 256 < NB) gbase[t + 256] = (int)Hs[(size_t)(t + 256) * NBLK + blk] - (int)l1;
    __syncthreads();
    for (int i = lo + t; i < hi; i += 256) {
        uint row = (uint)ei[i];
        uint col = (uint)ei[E + i];
        uint b = col >> 8;
        uint rec = (row << 10) | ((col & 255u) << 2) | (uint)wclass[i];
        uint slot = atomicAdd(&cursor[b], 1u);
        recs[slot] = rec;
        sbkt[slot] = (ushort)b;
    }
    __syncthreads();
    for (int s = t; s < cntTot; s += 256)
        recSorted[gbase[sbkt[s]] + s] = recs[s];
}

// K2: per-bucket node stats: cnt, startv (node-exact global CSR offset), dis = rsqrt(deg+1)
__global__ __launch_bounds__(256) void k2_stats(
        const uint* __restrict__ recSorted, const uint* __restrict__ Hs,
        const uint* __restrict__ spq,
        uint* __restrict__ cnt, uint* __restrict__ startv, float* __restrict__ dis,
        int E, int NB, int NBLK, int n_nodes) {
    __shared__ uint hcnt[256], hdeg[256], sA[256], sB[256];
    __shared__ uint sq[4];
    int b = blockIdx.x, t = threadIdx.x;
    hcnt[t] = 0; hdeg[t] = 0;
    if (t < 4) sq[t] = spq[t];
    __syncthreads();
    uint lo = Hs[(size_t)b * NBLK];
    uint hi = (b + 1 < NB) ? Hs[(size_t)(b + 1) * NBLK] : (uint)E;
    for (uint i = lo + t; i < hi; i += 256) {
        uint r = recSorted[i];
        atomicAdd(&hcnt[(r >> 2) & 255u], 1u);
        atomicAdd(&hdeg[(r >> 2) & 255u], sq[r & 3u]);
    }
    __syncthreads();
    uint* src = sA; uint* dst = sB;
    src[t] = hcnt[t];
    __syncthreads();
    for (int off = 1; off < 256; off <<= 1) {
        dst[t] = src[t] + ((t >= off) ? src[t - off] : 0u);
        __syncthreads();
        uint* tmp = src; src = dst; dst = tmp;
    }
    uint excl = (t == 0) ? 0u : src[t - 1];
    int node = (b << 8) + t;
    if (node < n_nodes) {
        cnt[node] = hcnt[t];
        startv[node] = lo + excl;
        float deg = (float)hdeg[t] * (1.0f / DEG_SCALE) + 1.0f;
        dis[node] = rsqrtf(deg);
    }
}

// K4: second-level partition + payload fill. payload = row<<15 | round(norm*32768)
__global__ __launch_bounds__(256) void k4_payload(
        const uint* __restrict__ recSorted, const uint* __restrict__ Hs,
        const float* __restrict__ sp, const float* __restrict__ dis,
        const uint* __restrict__ startv,
        uint* __restrict__ payload, int E, int NB, int NBLK, int n_nodes) {
    __shared__ float disl[256];
    __shared__ uint cur[256];
    __shared__ float spl[4];
    int b = blockIdx.x, t = threadIdx.x;
    int node = (b << 8) + t;
    disl[t] = (node < n_nodes) ? dis[node] : 0.0f;
    cur[t]  = (node < n_nodes) ? startv[node] : 0u;
    if (t < 4) spl[t] = sp[t];
    __syncthreads();
    uint lo = Hs[(size_t)b * NBLK];
    uint hi = (b + 1 < NB) ? Hs[(size_t)(b + 1) * NBLK] : (uint)E;
    for (uint i = lo + t; i < hi; i += 256) {
        uint r = recSorted[i];
        uint row = r >> 10;
        uint c = (r >> 2) & 255u;
        float nrm = dis[row] * spl[r & 3u] * disl[c];
        uint pos = atomicAdd(&cur[c], 1u);
        payload[pos] = (row << 15) | __float2uint_rn(nrm * NRM_SCALE);
    }
}

// h2 = x @ W_eff + b_eff, stored fp16 (stride-64 padded, zeros at d>=61).
// First blocks also zero-init pooled (runs before gather).
__global__ void h2_kernel(const float* __restrict__ x, const float* __restrict__ W_eff,
                          const float* __restrict__ b_eff,
                          __half* __restrict__ h2, float* __restrict__ pooled, int g64,
                          int n_nodes) {
    int gid = blockIdx.x * 256 + threadIdx.x;
    if (gid < g64) pooled[gid] = 0.0f;
    int node = blockIdx.x * 4 + (threadIdx.x >> 6);
    int d = threadIdx.x & 63;
    if (node >= n_nodes) return;
    float v = 0.f;
    if (d < HGCN) {
        v = b_eff[d];
#pragma unroll
        for (int f = 0; f < F_IN; ++f)
            v += x[node * F_IN + f] * W_eff[f * 64 + d];
    }
    h2[node * 64 + d] = __float2half(v);
}

// gather + gelu + pool. 4 edges/wave per load inst (quad layout) with TRANSPOSED epilogue:
// final atomic is ONE instruction with 61 contiguous active lanes (merges into ~4 lines/node).
__global__ void gather_pool_kernel(const uint* __restrict__ payload,
                                   const uint* __restrict__ startv, const uint* __restrict__ cnt,
                                   const float* __restrict__ dis,
                                   const uint2* __restrict__ h2q,
                                   const float* __restrict__ b_gcn, const int* __restrict__ batch,
                                   float* __restrict__ pooled, int n_nodes) {
    int node = blockIdx.x * 4 + (threadIdx.x >> 6);
    int lane = threadIdx.x & 63;
    int g4  = lane >> 4;        // edge offset within quad
    int s16 = lane & 15;        // dim-quad index: dims 4*s16 .. 4*s16+3
    if (node >= n_nodes) return;
    int s = (int)startv[node];
    int m = (int)cnt[node];
    const float inv = 1.0f / NRM_SCALE;
    float a0 = 0.f, a1 = 0.f, a2 = 0.f, a3 = 0.f;
    if (g4 == 0) {              // self-loop term only in group 0
        float di = dis[node];
        uint2 q = h2q[node * 16 + s16];
        float2 lo = __half22float2(*(const __half2*)&q.x);
        float2 hi = __half22float2(*(const __half2*)&q.y);
        float d2 = di * di;
        a0 = d2 * lo.x; a1 = d2 * lo.y; a2 = d2 * hi.x; a3 = d2 * hi.y;
    }
    for (int j0 = 0; j0 < m; j0 += 64) {
        uint p = 0;
        if (j0 + lane < m) p = payload[s + j0 + lane];  // coalesced 256B chunk load
        int lim = min(64, m - j0);
        int nq = (lim + 3) >> 2;
        int k = 0;
        for (; k + 8 <= nq; k += 8) {                   // 8 load insts = 32 edges in flight
            uint p0 = __shfl(p, 4 * (k + 0) + g4);
            uint p1 = __shfl(p, 4 * (k + 1) + g4);
            uint p2 = __shfl(p, 4 * (k + 2) + g4);
            uint p3 = __shfl(p, 4 * (k + 3) + g4);
            uint p4 = __shfl(p, 4 * (k + 4) + g4);
            uint p5 = __shfl(p, 4 * (k + 5) + g4);
            uint p6 = __shfl(p, 4 * (k + 6) + g4);
            uint p7 = __shfl(p, 4 * (k + 7) + g4);
            uint2 q0 = h2q[(p0 >> 15) * 16 + s16];
            uint2 q1 = h2q[(p1 >> 15) * 16 + s16];
            uint2 q2 = h2q[(p2 >> 15) * 16 + s16];
            uint2 q3 = h2q[(p3 >> 15) * 16 + s16];
            uint2 q4 = h2q[(p4 >> 15) * 16 + s16];
            uint2 q5 = h2q[(p5 >> 15) * 16 + s16];
            uint2 q6 = h2q[(p6 >> 15) * 16 + s16];
            uint2 q7 = h2q[(p7 >> 15) * 16 + s16];
#define ACC(pi, qi)                                                        \
            {                                                              \
                float w = (float)(pi & 32767u) * inv;                      \
                float2 lo = __half22float2(*(const __half2*)&qi.x);        \
                float2 hi = __half22float2(*(const __half2*)&qi.y);        \
                a0 += w * lo.x; a1 += w * lo.y;                            \
                a2 += w * hi.x; a3 += w * hi.y;                            \
            }
            ACC(p0, q0) ACC(p1, q1) ACC(p2, q2) ACC(p3, q3)
            ACC(p4, q4) ACC(p5, q5) ACC(p6, q6) ACC(p7, q7)
        }
        for (; k < nq; ++k) {
            uint pk = __shfl(p, 4 * k + g4);
            uint2 qk = h2q[(pk >> 15) * 16 + s16];
            ACC(pk, qk)
        }
#undef ACC
    }
    // combine the 4 edge groups (lanes s16+16g hold partials of same dims)
    a0 += __shfl_xor(a0, 16); a0 += __shfl_xor(a0, 32);
    a1 += __shfl_xor(a1, 16); a1 += __shfl_xor(a1, 32);
    a2 += __shfl_xor(a2, 16); a2 += __shfl_xor(a2, 32);
    a3 += __shfl_xor(a3, 16); a3 += __shfl_xor(a3, 32);
    // transpose: lane l needs dim l = quad (l>>2), element (l&3)
    int srcLane = lane >> 2;
    float b0 = __shfl(a0, srcLane);
    float b1 = __shfl(a1, srcLane);
    float b2 = __shfl(a2, srcLane);
    float b3 = __shfl(a3, srcLane);
    int j = lane & 3;
    float val = (j == 0) ? b0 : (j == 1) ? b1 : (j == 2) ? b2 : b3;
    // single contiguous atomic: 61 active lanes merge into ~4 line transactions
    if (lane < HGCN) {
        float v = gelu_exact(val + b_gcn[lane]);
        atomic_add_f32(&pooled[batch[node] * 64 + lane], v);
    }
}

// per-graph head
__global__ void final_kernel(const float* __restrict__ pooled,
                             const float* __restrict__ fn_avg,
                             const float* __restrict__ inf_rate,
                             const float* __restrict__ W_fn1, const float* __restrict__ b_fn1,
                             const float* __restrict__ W_fn2, const float* __restrict__ b_fn2,
                             const float* __restrict__ W_bb1, const float* __restrict__ b_bb1,
                             const float* __restrict__ W_out, const float* __restrict__ b_out,
                             float* __restrict__ logits) {
    __shared__ float z[64];
    __shared__ float t1[16];
    int g = blockIdx.x;
    int t = threadIdx.x;
    if (t < HGCN) z[t] = pooled[g * 64 + t];
    float e0 = fn_avg[g * 2], e1 = fn_avg[g * 2 + 1], e2 = inf_rate[g];
    if (t < 16) {
        float a = e0 * W_fn1[t] + e1 * W_fn1[16 + t] + e2 * W_fn1[32 + t] + b_fn1[t];
        t1[t] = gelu_exact(a);
    }
    __syncthreads();
    if (t < 3) {
        float a = b_fn2[t];
#pragma unroll
        for (int k = 0; k < 16; ++k) a += t1[k] * W_fn2[k * 3 + t];
        z[HGCN + t] = a;
    }
    __syncthreads();
    float acc = b_bb1[t];
#pragma unroll 8
    for (int k = 0; k < 64; ++k) acc += z[k] * W_bb1[k * 64 + t];
    float p = gelu_exact(acc) * W_out[t];
#pragma unroll
    for (int off = 32; off > 0; off >>= 1) p += __shfl_down(p, off);
    if (t == 0) logits[g] = p + b_out[0];
}

extern "C" void kernel_launch(void* const* d_in, const int* in_sizes, int n_in,
                              void* d_out, int out_size, void* d_ws, size_t ws_size,
                              hipStream_t stream) {
    const float* x        = (const float*)d_in[0];
    const int*   ei       = (const int*)d_in[1];
    const int*   batch    = (const int*)d_in[2];
    const int*   known    = (const int*)d_in[3];
    const int*   unk      = (const int*)d_in[4];
    const int*   obs      = (const int*)d_in[5];
    const float* fn_avg   = (const float*)d_in[6];
    const float* inf_rate = (const float*)d_in[7];
    const float* msg_w    = (const float*)d_in[8];
    const float* W_emb    = (const float*)d_in[9];
    const float* b_emb    = (const float*)d_in[10];
    const float* W_gcn    = (const float*)d_in[11];
    const float* b_gcn    = (const float*)d_in[12];
    const float* W_fn1    = (const float*)d_in[13];
    const float* b_fn1    = (const float*)d_in[14];
    const float* W_fn2    = (const float*)d_in[15];
    const float* b_fn2    = (const float*)d_in[16];
    const float* W_bb1    = (const float*)d_in[17];
    const float* b_bb1    = (const float*)d_in[18];
    const float* W_out    = (const float*)d_in[19];
    const float* b_out    = (const float*)d_in[20];
    float* logits = (float*)d_out;

    const int n_nodes = in_sizes[0] / F_IN;
    const int E       = in_sizes[1] / 2;
    const int nk = in_sizes[3], nu = in_sizes[4], no = in_sizes[5];
    const int G = in_sizes[6] / 2;

    const int NB   = (n_nodes + 255) >> 8;
    const int NBLK = (E + PART_R - 1) / PART_R;
    const int L    = NB * NBLK;
    const int nbL  = (L + SCAN_CH - 1) / SCAN_CH;

    char* ws = (char*)d_ws;
    size_t off = 0;
    auto alloc = [&](size_t bytes) -> void* {
        void* p = ws + off;
        off += (bytes + 255) & ~size_t(255);
        return p;
    };
    uchar*  wclass    = (uchar*)alloc(sizeof(uchar) * (size_t)E);
    uint*   recSorted = (uint*)alloc(sizeof(uint) * (size_t)E);
    uint*   H         = (uint*)alloc(sizeof(uint) * (size_t)L);
    uint*   Hs        = (uint*)alloc(sizeof(uint) * (size_t)L);
    int*    bsum      = (int*)alloc(sizeof(int) * (size_t)(nbL + 1));
    __half* h2        = (__half*)alloc(sizeof(__half) * (size_t)n_nodes * 64);
    uint*   payload   = (uint*)alloc(sizeof(uint) * (size_t)E);
    uint*   cntv      = (uint*)alloc(sizeof(uint) * (size_t)n_nodes);
    uint*   startv    = (uint*)alloc(sizeof(uint) * (size_t)n_nodes);
    float*  dis       = (float*)alloc(sizeof(float) * (size_t)n_nodes);
    float*  pooled    = (float*)alloc(sizeof(float) * (size_t)G * 64);
    float*  W_eff     = (float*)alloc(sizeof(float) * F_IN * 64);
    float*  b_eff     = (float*)alloc(sizeof(float) * 64);
    float*  sp        = (float*)alloc(sizeof(float) * 4);
    uint*   spq       = (uint*)alloc(sizeof(uint) * 4);

    prep_kernel<<<1, 64, 0, stream>>>(msg_w, W_emb, b_emb, W_gcn, sp, spq, W_eff, b_eff);
    k1_hist<<<NBLK, 256, 0, stream>>>(ei, H, wclass, E, NB, NBLK);   // also zeroes wclass
    set_mask_u8<<<(nk + 255) / 256, 256, 0, stream>>>(wclass, known, 1, nk);
    set_mask_u8<<<(nu + 255) / 256, 256, 0, stream>>>(wclass, unk, 2, nu);
    set_mask_u8<<<(no + 255) / 256, 256, 0, stream>>>(wclass, obs, 3, no);
    scan_partial_kernel<<<nbL, 256, 0, stream>>>((const int*)H, (int*)Hs, bsum, L);
    scan_add_kernel<<<(L + 255) / 256, 256, 0, stream>>>((int*)Hs, bsum, L);
    k3_partition<<<NBLK, 256, 0, stream>>>(ei, wclass, Hs, recSorted, E, NB, NBLK);
    k2_stats<<<NB, 256, 0, stream>>>(recSorted, Hs, spq, cntv, startv, dis, E, NB, NBLK, n_nodes);
    h2_kernel<<<(n_nodes + 3) / 4, 256, 0, stream>>>(x, W_eff, b_eff, h2, pooled, G * 64, n_nodes);
    k4_payload<<<NB, 256, 0, stream>>>(recSorted, Hs, sp, dis, startv, payload, E, NB, NBLK, n_nodes);
    gather_pool_kernel<<<(n_nodes + 3) / 4, 256, 0, stream>>>(payload, startv, cntv, dis,
                                                              (const uint2*)h2, b_gcn, batch,
                                                              pooled, n_nodes);
    final_kernel<<<G, 64, 0, stream>>>(pooled, fn_avg, inf_rate, W_fn1, b_fn1,
                                       W_fn2, b_fn2, W_bb1, b_bb1, W_out, b_out, logits);
}

// Round 12
// 228.842 us; speedup vs baseline: 1.5483x; 1.0721x over previous
//
#include <hip/hip_runtime.h>
#include <hip/hip_fp16.h>
#include <math.h>

#define F_IN 12
#define NHID 64
#define HGCN 61
#define EMB_OUT 54
#define SCAN_CH 1024
#define PART_R 8192           // edge records per partition block (LDS-staged)
#define DEG_SCALE 32768.0f    // 2^15 fixed-point for weighted degree accumulation
#define W_SCALE 16384.0f      // 2^14 fixed-point for edge weight (w <= 1.0 -> fits 15 bits)

typedef unsigned int uint;
typedef unsigned short ushort;
typedef unsigned char uchar;

__device__ __forceinline__ float gelu_exact(float v) {
    return 0.5f * v * (1.0f + erff(v * 0.70710678118654752440f));
}

__device__ __forceinline__ void atomic_add_f32(float* p, float v) {
    unsafeAtomicAdd(p, v);   // hardware global_atomic_add_f32
}

// K1 + prep fused. Block 0 additionally computes: weight tables spq (deg, 2^15) and
// sq15 (2^14), W_eff/b_eff fold. All blocks: bucket histogram + wclass zero-init.
__global__ __launch_bounds__(256) void k1_hist_prep(
        const int* __restrict__ ei, uint* __restrict__ H, uchar* __restrict__ wclass,
        const float* __restrict__ msg_w, const float* __restrict__ W_emb,
        const float* __restrict__ b_emb, const float* __restrict__ W_gcn,
        uint* __restrict__ spq, uint* __restrict__ sq15,
        float* __restrict__ W_eff, float* __restrict__ b_eff,
        int E, int NB, int NBLK) {
    __shared__ uint hist[512];
    __shared__ float ssp[4];
    int blk = blockIdx.x, t = threadIdx.x;
    hist[t] = 0; hist[t + 256] = 0;
    if (blk == 0 && t == 0) {
        float m = fmaxf(msg_w[0], fmaxf(msg_w[1], msg_w[2]));
        float e0 = expf(msg_w[0] - m), e1 = expf(msg_w[1] - m), e2 = expf(msg_w[2] - m);
        float s = e0 + e1 + e2;
        ssp[0] = 1.0f; ssp[1] = e0 / s; ssp[2] = e1 / s; ssp[3] = e2 / s;
    }
    __syncthreads();
    if (blk == 0) {
        if (t < 4) {
            spq[t]  = __float2uint_rn(ssp[t] * DEG_SCALE);
            sq15[t] = __float2uint_rn(ssp[t] * W_SCALE);
        }
        if (t < HGCN) {
            float be = 0.f, w0 = 0.f, w1 = 0.f;
            for (int k = 0; k < EMB_OUT; ++k) {
                float g = W_gcn[k * HGCN + t];
                be += b_emb[k] * g;
                w0 += W_emb[k] * g;
                w1 += W_emb[EMB_OUT + k] * g;
            }
            b_eff[t] = be;
            W_eff[0 * 64 + t] = w0;
            W_eff[1 * 64 + t] = w1;
            for (int f = 2; f < F_IN; ++f)
                W_eff[f * 64 + t] = W_gcn[(EMB_OUT + f - 2) * HGCN + t];
        }
    }
    int lo = blk * PART_R, hi = min(lo + PART_R, E);
    for (int i = lo + t; i < hi; i += 256) {
        wclass[i] = 0;
        atomicAdd(&hist[((uint)ei[E + i]) >> 8], 1u);
    }
    __syncthreads();
    for (int b = t; b < NB; b += 256) H[(size_t)b * NBLK + blk] = hist[b];
}

// masks write weight-class bytes; later kernel wins (dispatch order) == torch indexed assign.
__global__ void set_mask_u8(uchar* __restrict__ wclass, const int* __restrict__ mask,
                            uchar v, int n) {
    int i = blockIdx.x * blockDim.x + threadIdx.x;
    if (i < n) wclass[mask[i]] = v;
}

// ---- exclusive scan (2 kernels)
__global__ void scan_partial_kernel(const int* __restrict__ cnt, int* __restrict__ startv,
                                    int* __restrict__ bsum, int n) {
    __shared__ int s[256];
    int t = threadIdx.x;
    int base = blockIdx.x * SCAN_CH + t * 4;
    int v0 = (base + 0 < n) ? cnt[base + 0] : 0;
    int v1 = (base + 1 < n) ? cnt[base + 1] : 0;
    int v2 = (base + 2 < n) ? cnt[base + 2] : 0;
    int v3 = (base + 3 < n) ? cnt[base + 3] : 0;
    int loc = v0 + v1 + v2 + v3;
    s[t] = loc;
    __syncthreads();
    for (int off = 1; off < 256; off <<= 1) {
        int u = (t >= off) ? s[t - off] : 0;
        __syncthreads();
        s[t] += u;
        __syncthreads();
    }
    int ex = s[t] - loc;
    if (t == 255) bsum[blockIdx.x] = s[255];   // raw block sum
    if (base + 0 < n) startv[base + 0] = ex;
    if (base + 1 < n) startv[base + 1] = ex + v0;
    if (base + 2 < n) startv[base + 2] = ex + v0 + v1;
    if (base + 3 < n) startv[base + 3] = ex + v0 + v1 + v2;
}

// scan_add with inline bsum prefix: block covers 256 indices, i/SCAN_CH constant per block.
__global__ void scan_add_kernel(int* __restrict__ startv, const int* __restrict__ bsum, int n) {
    __shared__ int soff;
    int b = blockIdx.x;
    if (threadIdx.x == 0) {
        int q = (b * 256) / SCAN_CH;
        int acc = 0;
        for (int j = 0; j < q; ++j) acc += bsum[j];
        soff = acc;
    }
    __syncthreads();
    int i = b * 256 + threadIdx.x;
    if (i < n) startv[i] += soff;
}

// K3: LDS-staged partition to BUCKET granularity.
// Pack rec = row<<10 | (col&255)<<2 | wclass; write bucket-grouped.
__global__ __launch_bounds__(256) void k3_partition(
        const int* __restrict__ ei, const uchar* __restrict__ wclass,
        const uint* __restrict__ Hs, uint* __restrict__ recSorted,
        int E, int NB, int NBLK) {
    __shared__ uint recs[PART_R];
    __shared__ ushort sbkt[PART_R];
    __shared__ uint hist[512];
    __shared__ uint scanA[512];
    __shared__ uint scanB[512];
    __shared__ int  gbase[512];
    __shared__ uint cursor[512];
    int blk = blockIdx.x, t = threadIdx.x;
    int lo = blk * PART_R, hi = min(lo + PART_R, E);
    int cntTot = hi - lo;
    hist[t] = 0; hist[t + 256] = 0;
    __syncthreads();
    for (int i = lo + t; i < hi; i += 256)
        atomicAdd(&hist[((uint)ei[E + i]) >> 8], 1u);
    __syncthreads();
    uint* src = scanA; uint* dst = scanB;
    src[t] = hist[t]; src[t + 256] = hist[t + 256];
    __syncthreads();
    for (int off = 1; off < 512; off <<= 1) {
        dst[t]       = src[t]       + ((t >= off)       ? src[t - off]       : 0u);
        dst[t + 256] = src[t + 256] + ((t + 256 >= off) ? src[t + 256 - off] : 0u);
        __syncthreads();
        uint* tmp = src; src = dst; dst = tmp;
    }
    uint l0 = (t == 0) ? 0u : src[t - 1];
    uint l1 = src[t + 255];
    cursor[t] = l0; cursor[t + 256] = l1;
    if (t < NB)       gbase[t]       = (int)Hs[(size_t)t * NBLK + blk]         - (int)l0;
    if (t + 256 < NB) gbase[t + 256] = (int)Hs[(size_t)(t + 256) * NBLK + blk] - (int)l1;
    __syncthreads();
    for (int i = lo + t; i < hi; i += 256) {
        uint row = (uint)ei[i];
        uint col = (uint)ei[E + i];
        uint b = col >> 8;
        uint rec = (row << 10) | ((col & 255u) << 2) | (uint)wclass[i];
        uint slot = atomicAdd(&cursor[b], 1u);
        recs[slot] = rec;
        sbkt[slot] = (ushort)b;
    }
    __syncthreads();
    for (int s = t; s < cntTot; s += 256)
        recSorted[gbase[sbkt[s]] + s] = recs[s];
}

// K2: per-bucket node stats: cnt, startv (node-exact global CSR offset), dis = rsqrt(deg+1)
__global__ __launch_bounds__(256) void k2_stats(
        const uint* __restrict__ recSorted, const uint* __restrict__ Hs,
        const uint* __restrict__ spq,
        uint* __restrict__ cnt, uint* __restrict__ startv, float* __restrict__ dis,
        int E, int NB, int NBLK, int n_nodes) {
    __shared__ uint hcnt[256], hdeg[256], sA[256], sB[256];
    __shared__ uint sq[4];
    int b = blockIdx.x, t = threadIdx.x;
    hcnt[t] = 0; hdeg[t] = 0;
    if (t < 4) sq[t] = spq[t];
    __syncthreads();
    uint lo = Hs[(size_t)b * NBLK];
    uint hi = (b + 1 < NB) ? Hs[(size_t)(b + 1) * NBLK] : (uint)E;
    for (uint i = lo + t; i < hi; i += 256) {
        uint r = recSorted[i];
        atomicAdd(&hcnt[(r >> 2) & 255u], 1u);
        atomicAdd(&hdeg[(r >> 2) & 255u], sq[r & 3u]);
    }
    __syncthreads();
    uint* src = sA; uint* dst = sB;
    src[t] = hcnt[t];
    __syncthreads();
    for (int off = 1; off < 256; off <<= 1) {
        dst[t] = src[t] + ((t >= off) ? src[t - off] : 0u);
        __syncthreads();
        uint* tmp = src; src = dst; dst = tmp;
    }
    uint excl = (t == 0) ? 0u : src[t - 1];
    int node = (b << 8) + t;
    if (node < n_nodes) {
        cnt[node] = hcnt[t];
        startv[node] = lo + excl;
        float deg = (float)hdeg[t] * (1.0f / DEG_SCALE) + 1.0f;
        dis[node] = rsqrtf(deg);
    }
}

// K4: pure second-level permutation. payload = row<<15 | sq15[wcls] (no float math,
// no random dis gather -- dis is pre-folded into h2'). Writes stay in bucket window.
__global__ __launch_bounds__(256) void k4_payload(
        const uint* __restrict__ recSorted, const uint* __restrict__ Hs,
        const uint* __restrict__ sq15, const uint* __restrict__ startv,
        uint* __restrict__ payload, int E, int NB, int NBLK, int n_nodes) {
    __shared__ uint cur[256];
    __shared__ uint wq[4];
    int b = blockIdx.x, t = threadIdx.x;
    int node = (b << 8) + t;
    cur[t] = (node < n_nodes) ? startv[node] : 0u;
    if (t < 4) wq[t] = sq15[t];
    __syncthreads();
    uint lo = Hs[(size_t)b * NBLK];
    uint hi = (b + 1 < NB) ? Hs[(size_t)(b + 1) * NBLK] : (uint)E;
    for (uint i = lo + t; i < hi; i += 256) {
        uint r = recSorted[i];
        uint pos = atomicAdd(&cur[(r >> 2) & 255u], 1u);
        payload[pos] = ((r >> 10) << 15) | wq[r & 3u];
    }
}

// h2' = dis[node] * (x @ W_eff + b_eff), stored fp16 (stride-64 padded, zeros at d>=61).
// First blocks also zero-init pooled (runs before gather). Requires dis (after k2).
__global__ void h2_kernel(const float* __restrict__ x, const float* __restrict__ W_eff,
                          const float* __restrict__ b_eff, const float* __restrict__ dis,
                          __half* __restrict__ h2, float* __restrict__ pooled, int g64,
                          int n_nodes) {
    int gid = blockIdx.x * 256 + threadIdx.x;
    if (gid < g64) pooled[gid] = 0.0f;
    int node = blockIdx.x * 4 + (threadIdx.x >> 6);
    int d = threadIdx.x & 63;
    if (node >= n_nodes) return;
    float v = 0.f;
    if (d < HGCN) {
        v = b_eff[d];
#pragma unroll
        for (int f = 0; f < F_IN; ++f)
            v += x[node * F_IN + f] * W_eff[f * 64 + d];
        v *= dis[node];
    }
    h2[node * 64 + d] = __float2half(v);
}

// gather + gelu + pool (R9 structure: 2 edges/wave via pair groups, 8-deep unroll).
// h2' is pre-scaled by dis[row]; dis[col] applied once in the epilogue.
__global__ void gather_pool_kernel(const uint* __restrict__ payload,
                                   const uint* __restrict__ startv, const uint* __restrict__ cnt,
                                   const float* __restrict__ dis,
                                   const __half2* __restrict__ h2v,
                                   const float* __restrict__ b_gcn, const int* __restrict__ batch,
                                   float* __restrict__ pooled, int n_nodes) {
    int node = blockIdx.x * 4 + (threadIdx.x >> 6);
    int lane = threadIdx.x & 63;
    int g = lane >> 5;          // edge-parity group
    int sub = lane & 31;        // dim pair index (dims 2*sub, 2*sub+1)
    if (node >= n_nodes) return;
    int s = (int)startv[node];
    int m = (int)cnt[node];
    const float inv = 1.0f / W_SCALE;
    float accx = 0.f, accy = 0.f;
    if (g == 0) {               // self-loop: dis^2*h2 = dis * h2' -> h2' here, *dis at end
        float2 hv = __half22float2(h2v[node * 32 + sub]);
        accx = hv.x;
        accy = hv.y;
    }
    for (int j0 = 0; j0 < m; j0 += 64) {
        uint p = 0;
        if (j0 + lane < m) p = payload[s + j0 + lane];  // coalesced 256B chunk load
        int lim = min(64, m - j0);
        int npairs = (lim + 1) >> 1;
        int k = 0;
        for (; k + 8 <= npairs; k += 8) {               // 8 loads in flight per group
            uint p0 = __shfl(p, 2 * (k + 0) + g);
            uint p1 = __shfl(p, 2 * (k + 1) + g);
            uint p2 = __shfl(p, 2 * (k + 2) + g);
            uint p3 = __shfl(p, 2 * (k + 3) + g);
            uint p4 = __shfl(p, 2 * (k + 4) + g);
            uint p5 = __shfl(p, 2 * (k + 5) + g);
            uint p6 = __shfl(p, 2 * (k + 6) + g);
            uint p7 = __shfl(p, 2 * (k + 7) + g);
            float2 h0 = __half22float2(h2v[(p0 >> 15) * 32 + sub]);
            float2 h1 = __half22float2(h2v[(p1 >> 15) * 32 + sub]);
            float2 h2f = __half22float2(h2v[(p2 >> 15) * 32 + sub]);
            float2 h3 = __half22float2(h2v[(p3 >> 15) * 32 + sub]);
            float2 h4 = __half22float2(h2v[(p4 >> 15) * 32 + sub]);
            float2 h5 = __half22float2(h2v[(p5 >> 15) * 32 + sub]);
            float2 h6 = __half22float2(h2v[(p6 >> 15) * 32 + sub]);
            float2 h7 = __half22float2(h2v[(p7 >> 15) * 32 + sub]);
            float w0 = (float)(p0 & 32767u) * inv;
            float w1 = (float)(p1 & 32767u) * inv;
            float w2 = (float)(p2 & 32767u) * inv;
            float w3 = (float)(p3 & 32767u) * inv;
            float w4 = (float)(p4 & 32767u) * inv;
            float w5 = (float)(p5 & 32767u) * inv;
            float w6 = (float)(p6 & 32767u) * inv;
            float w7 = (float)(p7 & 32767u) * inv;
            accx += w0 * h0.x; accy += w0 * h0.y;
            accx += w1 * h1.x; accy += w1 * h1.y;
            accx += w2 * h2f.x; accy += w2 * h2f.y;
            accx += w3 * h3.x; accy += w3 * h3.y;
            accx += w4 * h4.x; accy += w4 * h4.y;
            accx += w5 * h5.x; accy += w5 * h5.y;
            accx += w6 * h6.x; accy += w6 * h6.y;
            accx += w7 * h7.x; accy += w7 * h7.y;
        }
        for (; k < npairs; ++k) {
            uint pk = __shfl(p, 2 * k + g);
            float2 hk = __half22float2(h2v[(pk >> 15) * 32 + sub]);
            float wk = (float)(pk & 32767u) * inv;
            accx += wk * hk.x; accy += wk * hk.y;
        }
    }
    // combine the two edge-parity groups
    accx += __shfl_xor(accx, 32);
    accy += __shfl_xor(accy, 32);
    // epilogue: group 0 writes even dim, group 1 writes odd dim; apply dis[col] once
    int d = 2 * sub + g;
    float val = (g ? accy : accx) * dis[node];
    if (d < HGCN) {
        float v = gelu_exact(val + b_gcn[d]);
        atomic_add_f32(&pooled[batch[node] * 64 + d], v);
    }
}

// per-graph head
__global__ void final_kernel(const float* __restrict__ pooled,
                             const float* __restrict__ fn_avg,
                             const float* __restrict__ inf_rate,
                             const float* __restrict__ W_fn1, const float* __restrict__ b_fn1,
                             const float* __restrict__ W_fn2, const float* __restrict__ b_fn2,
                             const float* __restrict__ W_bb1, const float* __restrict__ b_bb1,
                             const float* __restrict__ W_out, const float* __restrict__ b_out,
                             float* __restrict__ logits) {
    __shared__ float z[64];
    __shared__ float t1[16];
    int g = blockIdx.x;
    int t = threadIdx.x;
    if (t < HGCN) z[t] = pooled[g * 64 + t];
    float e0 = fn_avg[g * 2], e1 = fn_avg[g * 2 + 1], e2 = inf_rate[g];
    if (t < 16) {
        float a = e0 * W_fn1[t] + e1 * W_fn1[16 + t] + e2 * W_fn1[32 + t] + b_fn1[t];
        t1[t] = gelu_exact(a);
    }
    __syncthreads();
    if (t < 3) {
        float a = b_fn2[t];
#pragma unroll
        for (int k = 0; k < 16; ++k) a += t1[k] * W_fn2[k * 3 + t];
        z[HGCN + t] = a;
    }
    __syncthreads();
    float acc = b_bb1[t];
#pragma unroll 8
    for (int k = 0; k < 64; ++k) acc += z[k] * W_bb1[k * 64 + t];
    float p = gelu_exact(acc) * W_out[t];
#pragma unroll
    for (int off = 32; off > 0; off >>= 1) p += __shfl_down(p, off);
    if (t == 0) logits[g] = p + b_out[0];
}

extern "C" void kernel_launch(void* const* d_in, const int* in_sizes, int n_in,
                              void* d_out, int out_size, void* d_ws, size_t ws_size,
                              hipStream_t stream) {
    const float* x        = (const float*)d_in[0];
    const int*   ei       = (const int*)d_in[1];
    const int*   batch    = (const int*)d_in[2];
    const int*   known    = (const int*)d_in[3];
    const int*   unk      = (const int*)d_in[4];
    const int*   obs      = (const int*)d_in[5];
    const float* fn_avg   = (const float*)d_in[6];
    const float* inf_rate = (const float*)d_in[7];
    const float* msg_w    = (const float*)d_in[8];
    const float* W_emb    = (const float*)d_in[9];
    const float* b_emb    = (const float*)d_in[10];
    const float* W_gcn    = (const float*)d_in[11];
    const float* b_gcn    = (const float*)d_in[12];
    const float* W_fn1    = (const float*)d_in[13];
    const float* b_fn1    = (const float*)d_in[14];
    const float* W_fn2    = (const float*)d_in[15];
    const float* b_fn2    = (const float*)d_in[16];
    const float* W_bb1    = (const float*)d_in[17];
    const float* b_bb1    = (const float*)d_in[18];
    const float* W_out    = (const float*)d_in[19];
    const float* b_out    = (const float*)d_in[20];
    float* logits = (float*)d_out;

    const int n_nodes = in_sizes[0] / F_IN;
    const int E       = in_sizes[1] / 2;
    const int nk = in_sizes[3], nu = in_sizes[4], no = in_sizes[5];
    const int G = in_sizes[6] / 2;

    const int NB   = (n_nodes + 255) >> 8;
    const int NBLK = (E + PART_R - 1) / PART_R;
    const int L    = NB * NBLK;
    const int nbL  = (L + SCAN_CH - 1) / SCAN_CH;

    char* ws = (char*)d_ws;
    size_t off = 0;
    auto alloc = [&](size_t bytes) -> void* {
        void* p = ws + off;
        off += (bytes + 255) & ~size_t(255);
        return p;
    };
    uchar*  wclass    = (uchar*)alloc(sizeof(uchar) * (size_t)E);
    uint*   recSorted = (uint*)alloc(sizeof(uint) * (size_t)E);
    uint*   H         = (uint*)alloc(sizeof(uint) * (size_t)L);
    uint*   Hs        = (uint*)alloc(sizeof(uint) * (size_t)L);
    int*    bsum      = (int*)alloc(sizeof(int) * (size_t)(nbL + 1));
    __half* h2        = (__half*)alloc(sizeof(__half) * (size_t)n_nodes * 64);
    uint*   payload   = (uint*)alloc(sizeof(uint) * (size_t)E);
    uint*   cntv      = (uint*)alloc(sizeof(uint) * (size_t)n_nodes);
    uint*   startv    = (uint*)alloc(sizeof(uint) * (size_t)n_nodes);
    float*  dis       = (float*)alloc(sizeof(float) * (size_t)n_nodes);
    float*  pooled    = (float*)alloc(sizeof(float) * (size_t)G * 64);
    float*  W_eff     = (float*)alloc(sizeof(float) * F_IN * 64);
    float*  b_eff     = (float*)alloc(sizeof(float) * 64);
    uint*   spq       = (uint*)alloc(sizeof(uint) * 4);
    uint*   sq15      = (uint*)alloc(sizeof(uint) * 4);

    k1_hist_prep<<<NBLK, 256, 0, stream>>>(ei, H, wclass, msg_w, W_emb, b_emb, W_gcn,
                                           spq, sq15, W_eff, b_eff, E, NB, NBLK);
    set_mask_u8<<<(nk + 255) / 256, 256, 0, stream>>>(wclass, known, 1, nk);
    set_mask_u8<<<(nu + 255) / 256, 256, 0, stream>>>(wclass, unk, 2, nu);
    set_mask_u8<<<(no + 255) / 256, 256, 0, stream>>>(wclass, obs, 3, no);
    scan_partial_kernel<<<nbL, 256, 0, stream>>>((const int*)H, (int*)Hs, bsum, L);
    scan_add_kernel<<<(L + 255) / 256, 256, 0, stream>>>((int*)Hs, bsum, L);
    k3_partition<<<NBLK, 256, 0, stream>>>(ei, wclass, Hs, recSorted, E, NB, NBLK);
    k2_stats<<<NB, 256, 0, stream>>>(recSorted, Hs, spq, cntv, startv, dis, E, NB, NBLK, n_nodes);
    h2_kernel<<<(n_nodes + 3) / 4, 256, 0, stream>>>(x, W_eff, b_eff, dis, h2, pooled,
                                                     G * 64, n_nodes);
    k4_payload<<<NB, 256, 0, stream>>>(recSorted, Hs, sq15, startv, payload, E, NB, NBLK, n_nodes);
    gather_pool_kernel<<<(n_nodes + 3) / 4, 256, 0, stream>>>(payload, startv, cntv, dis,
                                                              (const __half2*)h2, b_gcn, batch,
                                                              pooled, n_nodes);
    final_kernel<<<G, 64, 0, stream>>>(pooled, fn_avg, inf_rate, W_fn1, b_fn1,
                                       W_fn2, b_fn2, W_bb1, b_bb1, W_out, b_out, logits);
}

// Round 13
// 215.700 us; speedup vs baseline: 1.6427x; 1.0609x over previous
//
#include <hip/hip_runtime.h>
#include <hip/hip_fp16.h>
#include <math.h>

#define F_IN 12
#define NHID 64
#define HGCN 61
#define EMB_OUT 54
#define SCAN_CH 1024
#define PART_R 8192           // edge records per partition block (LDS-staged)
#define DEG_SCALE 32768.0f    // 2^15 fixed-point for weighted degree accumulation
#define W_SCALE 16384.0f      // 2^14 fixed-point for edge weight (w <= 1.0 -> fits 15 bits)

typedef unsigned int uint;
typedef unsigned short ushort;
typedef unsigned char uchar;

__device__ __forceinline__ float gelu_exact(float v) {
    return 0.5f * v * (1.0f + erff(v * 0.70710678118654752440f));
}

__device__ __forceinline__ void atomic_add_f32(float* p, float v) {
    unsafeAtomicAdd(p, v);   // hardware global_atomic_add_f32
}

// K1 + prep fused. Block 0 additionally computes: weight tables spq (deg, 2^15) and
// sq15 (2^14), W_eff/b_eff fold. All blocks: bucket histogram + wclass zero-init.
__global__ __launch_bounds__(256) void k1_hist_prep(
        const int* __restrict__ ei, uint* __restrict__ H, uchar* __restrict__ wclass,
        const float* __restrict__ msg_w, const float* __restrict__ W_emb,
        const float* __restrict__ b_emb, const float* __restrict__ W_gcn,
        uint* __restrict__ spq, uint* __restrict__ sq15,
        float* __restrict__ W_eff, float* __restrict__ b_eff,
        int E, int NB, int NBLK) {
    __shared__ uint hist[512];
    __shared__ float ssp[4];
    int blk = blockIdx.x, t = threadIdx.x;
    hist[t] = 0; hist[t + 256] = 0;
    if (blk == 0 && t == 0) {
        float m = fmaxf(msg_w[0], fmaxf(msg_w[1], msg_w[2]));
        float e0 = expf(msg_w[0] - m), e1 = expf(msg_w[1] - m), e2 = expf(msg_w[2] - m);
        float s = e0 + e1 + e2;
        ssp[0] = 1.0f; ssp[1] = e0 / s; ssp[2] = e1 / s; ssp[3] = e2 / s;
    }
    __syncthreads();
    if (blk == 0) {
        if (t < 4) {
            spq[t]  = __float2uint_rn(ssp[t] * DEG_SCALE);
            sq15[t] = __float2uint_rn(ssp[t] * W_SCALE);
        }
        if (t < HGCN) {
            float be = 0.f, w0 = 0.f, w1 = 0.f;
            for (int k = 0; k < EMB_OUT; ++k) {
                float g = W_gcn[k * HGCN + t];
                be += b_emb[k] * g;
                w0 += W_emb[k] * g;
                w1 += W_emb[EMB_OUT + k] * g;
            }
            b_eff[t] = be;
            W_eff[0 * 64 + t] = w0;
            W_eff[1 * 64 + t] = w1;
            for (int f = 2; f < F_IN; ++f)
                W_eff[f * 64 + t] = W_gcn[(EMB_OUT + f - 2) * HGCN + t];
        }
    }
    int lo = blk * PART_R, hi = min(lo + PART_R, E);
    for (int i = lo + t; i < hi; i += 256) {
        wclass[i] = 0;
        atomicAdd(&hist[((uint)ei[E + i]) >> 8], 1u);
    }
    __syncthreads();
    for (int b = t; b < NB; b += 256) H[(size_t)b * NBLK + blk] = hist[b];
}

// masks write weight-class bytes; later kernel wins (dispatch order) == torch indexed assign.
__global__ void set_mask_u8(uchar* __restrict__ wclass, const int* __restrict__ mask,
                            uchar v, int n) {
    int i = blockIdx.x * blockDim.x + threadIdx.x;
    if (i < n) wclass[mask[i]] = v;
}

// ---- exclusive scan (2 kernels)
__global__ void scan_partial_kernel(const int* __restrict__ cnt, int* __restrict__ startv,
                                    int* __restrict__ bsum, int n) {
    __shared__ int s[256];
    int t = threadIdx.x;
    int base = blockIdx.x * SCAN_CH + t * 4;
    int v0 = (base + 0 < n) ? cnt[base + 0] : 0;
    int v1 = (base + 1 < n) ? cnt[base + 1] : 0;
    int v2 = (base + 2 < n) ? cnt[base + 2] : 0;
    int v3 = (base + 3 < n) ? cnt[base + 3] : 0;
    int loc = v0 + v1 + v2 + v3;
    s[t] = loc;
    __syncthreads();
    for (int off = 1; off < 256; off <<= 1) {
        int u = (t >= off) ? s[t - off] : 0;
        __syncthreads();
        s[t] += u;
        __syncthreads();
    }
    int ex = s[t] - loc;
    if (t == 255) bsum[blockIdx.x] = s[255];   // raw block sum
    if (base + 0 < n) startv[base + 0] = ex;
    if (base + 1 < n) startv[base + 1] = ex + v0;
    if (base + 2 < n) startv[base + 2] = ex + v0 + v1;
    if (base + 3 < n) startv[base + 3] = ex + v0 + v1 + v2;
}

// scan_add with inline bsum prefix: block covers 256 indices, i/SCAN_CH constant per block.
__global__ void scan_add_kernel(int* __restrict__ startv, const int* __restrict__ bsum, int n) {
    __shared__ int soff;
    int b = blockIdx.x;
    if (threadIdx.x == 0) {
        int q = (b * 256) / SCAN_CH;
        int acc = 0;
        for (int j = 0; j < q; ++j) acc += bsum[j];
        soff = acc;
    }
    __syncthreads();
    int i = b * 256 + threadIdx.x;
    if (i < n) startv[i] += soff;
}

// K3: LDS-staged partition to BUCKET granularity. Own-block histogram comes from H
// (computed by k1) instead of re-reading ei -- saves a 12.8MB pass + 3.2M LDS atomics.
// Pack rec = row<<10 | (col&255)<<2 | wclass; write bucket-grouped.
__global__ __launch_bounds__(256) void k3_partition(
        const int* __restrict__ ei, const uchar* __restrict__ wclass,
        const uint* __restrict__ H, const uint* __restrict__ Hs,
        uint* __restrict__ recSorted, int E, int NB, int NBLK) {
    __shared__ uint recs[PART_R];
    __shared__ ushort sbkt[PART_R];
    __shared__ uint scanA[512];
    __shared__ uint scanB[512];
    __shared__ int  gbase[512];
    __shared__ uint cursor[512];
    int blk = blockIdx.x, t = threadIdx.x;
    int lo = blk * PART_R, hi = min(lo + PART_R, E);
    int cntTot = hi - lo;
    // seed per-block hist from k1's H (this block's column)
    uint h0 = (t < NB)       ? H[(size_t)t * NBLK + blk]         : 0u;
    uint h1 = (t + 256 < NB) ? H[(size_t)(t + 256) * NBLK + blk] : 0u;
    uint* src = scanA; uint* dst = scanB;
    src[t] = h0; src[t + 256] = h1;
    __syncthreads();
    for (int off = 1; off < 512; off <<= 1) {
        dst[t]       = src[t]       + ((t >= off)       ? src[t - off]       : 0u);
        dst[t + 256] = src[t + 256] + ((t + 256 >= off) ? src[t + 256 - off] : 0u);
        __syncthreads();
        uint* tmp = src; src = dst; dst = tmp;
    }
    uint l0 = (t == 0) ? 0u : src[t - 1];   // exclusive at t
    uint l1 = src[t + 255];                 // exclusive at t+256
    cursor[t] = l0; cursor[t + 256] = l1;
    if (t < NB)       gbase[t]       = (int)Hs[(size_t)t * NBLK + blk]         - (int)l0;
    if (t + 256 < NB) gbase[t + 256] = (int)Hs[(size_t)(t + 256) * NBLK + blk] - (int)l1;
    __syncthreads();
    for (int i = lo + t; i < hi; i += 256) {
        uint row = (uint)ei[i];
        uint col = (uint)ei[E + i];
        uint b = col >> 8;
        uint rec = (row << 10) | ((col & 255u) << 2) | (uint)wclass[i];
        uint slot = atomicAdd(&cursor[b], 1u);
        recs[slot] = rec;
        sbkt[slot] = (ushort)b;
    }
    __syncthreads();
    for (int s = t; s < cntTot; s += 256)
        recSorted[gbase[sbkt[s]] + s] = recs[s];
}

// K2+K4 merged: pass 1 computes per-node cnt/startv/dis (LDS hist + scan); pass 2
// re-reads the bucket's records (L1/L2-hot, ~32KB) and permutes into payload.
// payload = row<<15 | round(w * 2^14).
__global__ __launch_bounds__(256) void k2k4(
        const uint* __restrict__ recSorted, const uint* __restrict__ Hs,
        const uint* __restrict__ spq, const uint* __restrict__ sq15,
        uint* __restrict__ cnt, uint* __restrict__ startv, float* __restrict__ dis,
        uint* __restrict__ payload, int E, int NB, int NBLK, int n_nodes) {
    __shared__ uint hcnt[256], hdeg[256], sA[256], sB[256];
    __shared__ uint cur[256];
    __shared__ uint sq[4], wq[4];
    int b = blockIdx.x, t = threadIdx.x;
    hcnt[t] = 0; hdeg[t] = 0;
    if (t < 4) { sq[t] = spq[t]; wq[t] = sq15[t]; }
    __syncthreads();
    uint lo = Hs[(size_t)b * NBLK];
    uint hi = (b + 1 < NB) ? Hs[(size_t)(b + 1) * NBLK] : (uint)E;
    for (uint i = lo + t; i < hi; i += 256) {
        uint r = recSorted[i];
        atomicAdd(&hcnt[(r >> 2) & 255u], 1u);
        atomicAdd(&hdeg[(r >> 2) & 255u], sq[r & 3u]);
    }
    __syncthreads();
    uint* src = sA; uint* dst = sB;
    src[t] = hcnt[t];
    __syncthreads();
    for (int off = 1; off < 256; off <<= 1) {
        dst[t] = src[t] + ((t >= off) ? src[t - off] : 0u);
        __syncthreads();
        uint* tmp = src; src = dst; dst = tmp;
    }
    uint excl = (t == 0) ? 0u : src[t - 1];
    int node = (b << 8) + t;
    if (node < n_nodes) {
        cnt[node] = hcnt[t];
        startv[node] = lo + excl;
        float deg = (float)hdeg[t] * (1.0f / DEG_SCALE) + 1.0f;
        dis[node] = rsqrtf(deg);
    }
    cur[t] = lo + excl;
    __syncthreads();
    for (uint i = lo + t; i < hi; i += 256) {
        uint r = recSorted[i];
        uint pos = atomicAdd(&cur[(r >> 2) & 255u], 1u);
        payload[pos] = ((r >> 10) << 15) | wq[r & 3u];
    }
}

// h2' = dis[node] * (x @ W_eff + b_eff), stored fp16 (stride-64 padded, zeros at d>=61).
// First blocks also zero-init pooled (runs before gather). Requires dis (after k2k4).
__global__ void h2_kernel(const float* __restrict__ x, const float* __restrict__ W_eff,
                          const float* __restrict__ b_eff, const float* __restrict__ dis,
                          __half* __restrict__ h2, float* __restrict__ pooled, int g64,
                          int n_nodes) {
    int gid = blockIdx.x * 256 + threadIdx.x;
    if (gid < g64) pooled[gid] = 0.0f;
    int node = blockIdx.x * 4 + (threadIdx.x >> 6);
    int d = threadIdx.x & 63;
    if (node >= n_nodes) return;
    float v = 0.f;
    if (d < HGCN) {
        v = b_eff[d];
#pragma unroll
        for (int f = 0; f < F_IN; ++f)
            v += x[node * F_IN + f] * W_eff[f * 64 + d];
        v *= dis[node];
    }
    h2[node * 64 + d] = __float2half(v);
}

// gather + gelu + pool (R9 structure: 2 edges/wave via pair groups, 8-deep unroll).
// h2' is pre-scaled by dis[row]; dis[col] applied once in the epilogue.
__global__ void gather_pool_kernel(const uint* __restrict__ payload,
                                   const uint* __restrict__ startv, const uint* __restrict__ cnt,
                                   const float* __restrict__ dis,
                                   const __half2* __restrict__ h2v,
                                   const float* __restrict__ b_gcn, const int* __restrict__ batch,
                                   float* __restrict__ pooled, int n_nodes) {
    int node = blockIdx.x * 4 + (threadIdx.x >> 6);
    int lane = threadIdx.x & 63;
    int g = lane >> 5;          // edge-parity group
    int sub = lane & 31;        // dim pair index (dims 2*sub, 2*sub+1)
    if (node >= n_nodes) return;
    int s = (int)startv[node];
    int m = (int)cnt[node];
    const float inv = 1.0f / W_SCALE;
    float accx = 0.f, accy = 0.f;
    if (g == 0) {               // self-loop: dis^2*h2 = dis * h2' -> h2' here, *dis at end
        float2 hv = __half22float2(h2v[node * 32 + sub]);
        accx = hv.x;
        accy = hv.y;
    }
    for (int j0 = 0; j0 < m; j0 += 64) {
        uint p = 0;
        if (j0 + lane < m) p = payload[s + j0 + lane];  // coalesced 256B chunk load
        int lim = min(64, m - j0);
        int npairs = (lim + 1) >> 1;
        int k = 0;
        for (; k + 8 <= npairs; k += 8) {               // 8 loads in flight per group
            uint p0 = __shfl(p, 2 * (k + 0) + g);
            uint p1 = __shfl(p, 2 * (k + 1) + g);
            uint p2 = __shfl(p, 2 * (k + 2) + g);
            uint p3 = __shfl(p, 2 * (k + 3) + g);
            uint p4 = __shfl(p, 2 * (k + 4) + g);
            uint p5 = __shfl(p, 2 * (k + 5) + g);
            uint p6 = __shfl(p, 2 * (k + 6) + g);
            uint p7 = __shfl(p, 2 * (k + 7) + g);
            float2 h0 = __half22float2(h2v[(p0 >> 15) * 32 + sub]);
            float2 h1 = __half22float2(h2v[(p1 >> 15) * 32 + sub]);
            float2 h2f = __half22float2(h2v[(p2 >> 15) * 32 + sub]);
            float2 h3 = __half22float2(h2v[(p3 >> 15) * 32 + sub]);
            float2 h4 = __half22float2(h2v[(p4 >> 15) * 32 + sub]);
            float2 h5 = __half22float2(h2v[(p5 >> 15) * 32 + sub]);
            float2 h6 = __half22float2(h2v[(p6 >> 15) * 32 + sub]);
            float2 h7 = __half22float2(h2v[(p7 >> 15) * 32 + sub]);
            float w0 = (float)(p0 & 32767u) * inv;
            float w1 = (float)(p1 & 32767u) * inv;
            float w2 = (float)(p2 & 32767u) * inv;
            float w3 = (float)(p3 & 32767u) * inv;
            float w4 = (float)(p4 & 32767u) * inv;
            float w5 = (float)(p5 & 32767u) * inv;
            float w6 = (float)(p6 & 32767u) * inv;
            float w7 = (float)(p7 & 32767u) * inv;
            accx += w0 * h0.x; accy += w0 * h0.y;
            accx += w1 * h1.x; accy += w1 * h1.y;
            accx += w2 * h2f.x; accy += w2 * h2f.y;
            accx += w3 * h3.x; accy += w3 * h3.y;
            accx += w4 * h4.x; accy += w4 * h4.y;
            accx += w5 * h5.x; accy += w5 * h5.y;
            accx += w6 * h6.x; accy += w6 * h6.y;
            accx += w7 * h7.x; accy += w7 * h7.y;
        }
        for (; k < npairs; ++k) {
            uint pk = __shfl(p, 2 * k + g);
            float2 hk = __half22float2(h2v[(pk >> 15) * 32 + sub]);
            float wk = (float)(pk & 32767u) * inv;
            accx += wk * hk.x; accy += wk * hk.y;
        }
    }
    // combine the two edge-parity groups
    accx += __shfl_xor(accx, 32);
    accy += __shfl_xor(accy, 32);
    // epilogue: group 0 writes even dim, group 1 writes odd dim; apply dis[col] once
    int d = 2 * sub + g;
    float val = (g ? accy : accx) * dis[node];
    if (d < HGCN) {
        float v = gelu_exact(val + b_gcn[d]);
        atomic_add_f32(&pooled[batch[node] * 64 + d], v);
    }
}

// per-graph head
__global__ void final_kernel(const float* __restrict__ pooled,
                             const float* __restrict__ fn_avg,
                             const float* __restrict__ inf_rate,
                             const float* __restrict__ W_fn1, const float* __restrict__ b_fn1,
                             const float* __restrict__ W_fn2, const float* __restrict__ b_fn2,
                             const float* __restrict__ W_bb1, const float* __restrict__ b_bb1,
                             const float* __restrict__ W_out, const float* __restrict__ b_out,
                             float* __restrict__ logits) {
    __shared__ float z[64];
    __shared__ float t1[16];
    int g = blockIdx.x;
    int t = threadIdx.x;
    if (t < HGCN) z[t] = pooled[g * 64 + t];
    float e0 = fn_avg[g * 2], e1 = fn_avg[g * 2 + 1], e2 = inf_rate[g];
    if (t < 16) {
        float a = e0 * W_fn1[t] + e1 * W_fn1[16 + t] + e2 * W_fn1[32 + t] + b_fn1[t];
        t1[t] = gelu_exact(a);
    }
    __syncthreads();
    if (t < 3) {
        float a = b_fn2[t];
#pragma unroll
        for (int k = 0; k < 16; ++k) a += t1[k] * W_fn2[k * 3 + t];
        z[HGCN + t] = a;
    }
    __syncthreads();
    float acc = b_bb1[t];
#pragma unroll 8
    for (int k = 0; k < 64; ++k) acc += z[k] * W_bb1[k * 64 + t];
    float p = gelu_exact(acc) * W_out[t];
#pragma unroll
    for (int off = 32; off > 0; off >>= 1) p += __shfl_down(p, off);
    if (t == 0) logits[g] = p + b_out[0];
}

extern "C" void kernel_launch(void* const* d_in, const int* in_sizes, int n_in,
                              void* d_out, int out_size, void* d_ws, size_t ws_size,
                              hipStream_t stream) {
    const float* x        = (const float*)d_in[0];
    const int*   ei       = (const int*)d_in[1];
    const int*   batch    = (const int*)d_in[2];
    const int*   known    = (const int*)d_in[3];
    const int*   unk      = (const int*)d_in[4];
    const int*   obs      = (const int*)d_in[5];
    const float* fn_avg   = (const float*)d_in[6];
    const float* inf_rate = (const float*)d_in[7];
    const float* msg_w    = (const float*)d_in[8];
    const float* W_emb    = (const float*)d_in[9];
    const float* b_emb    = (const float*)d_in[10];
    const float* W_gcn    = (const float*)d_in[11];
    const float* b_gcn    = (const float*)d_in[12];
    const float* W_fn1    = (const float*)d_in[13];
    const float* b_fn1    = (const float*)d_in[14];
    const float* W_fn2    = (const float*)d_in[15];
    const float* b_fn2    = (const float*)d_in[16];
    const float* W_bb1    = (const float*)d_in[17];
    const float* b_bb1    = (const float*)d_in[18];
    const float* W_out    = (const float*)d_in[19];
    const float* b_out    = (const float*)d_in[20];
    float* logits = (float*)d_out;

    const int n_nodes = in_sizes[0] / F_IN;
    const int E       = in_sizes[1] / 2;
    const int nk = in_sizes[3], nu = in_sizes[4], no = in_sizes[5];
    const int G = in_sizes[6] / 2;

    const int NB   = (n_nodes + 255) >> 8;
    const int NBLK = (E + PART_R - 1) / PART_R;
    const int L    = NB * NBLK;
    const int nbL  = (L + SCAN_CH - 1) / SCAN_CH;

    char* ws = (char*)d_ws;
    size_t off = 0;
    auto alloc = [&](size_t bytes) -> void* {
        void* p = ws + off;
        off += (bytes + 255) & ~size_t(255);
        return p;
    };
    uchar*  wclass    = (uchar*)alloc(sizeof(uchar) * (size_t)E);
    uint*   recSorted = (uint*)alloc(sizeof(uint) * (size_t)E);
    uint*   H         = (uint*)alloc(sizeof(uint) * (size_t)L);
    uint*   Hs        = (uint*)alloc(sizeof(uint) * (size_t)L);
    int*    bsum      = (int*)alloc(sizeof(int) * (size_t)(nbL + 1));
    __half* h2        = (__half*)alloc(sizeof(__half) * (size_t)n_nodes * 64);
    uint*   payload   = (uint*)alloc(sizeof(uint) * (size_t)E);
    uint*   cntv      = (uint*)alloc(sizeof(uint) * (size_t)n_nodes);
    uint*   startv    = (uint*)alloc(sizeof(uint) * (size_t)n_nodes);
    float*  dis       = (float*)alloc(sizeof(float) * (size_t)n_nodes);
    float*  pooled    = (float*)alloc(sizeof(float) * (size_t)G * 64);
    float*  W_eff     = (float*)alloc(sizeof(float) * F_IN * 64);
    float*  b_eff     = (float*)alloc(sizeof(float) * 64);
    uint*   spq       = (uint*)alloc(sizeof(uint) * 4);
    uint*   sq15      = (uint*)alloc(sizeof(uint) * 4);

    k1_hist_prep<<<NBLK, 256, 0, stream>>>(ei, H, wclass, msg_w, W_emb, b_emb, W_gcn,
                                           spq, sq15, W_eff, b_eff, E, NB, NBLK);
    set_mask_u8<<<(nk + 255) / 256, 256, 0, stream>>>(wclass, known, 1, nk);
    set_mask_u8<<<(nu + 255) / 256, 256, 0, stream>>>(wclass, unk, 2, nu);
    set_mask_u8<<<(no + 255) / 256, 256, 0, stream>>>(wclass, obs, 3, no);
    scan_partial_kernel<<<nbL, 256, 0, stream>>>((const int*)H, (int*)Hs, bsum, L);
    scan_add_kernel<<<(L + 255) / 256, 256, 0, stream>>>((int*)Hs, bsum, L);
    k3_partition<<<NBLK, 256, 0, stream>>>(ei, wclass, H, Hs, recSorted, E, NB, NBLK);
    k2k4<<<NB, 256, 0, stream>>>(recSorted, Hs, spq, sq15, cntv, startv, dis, payload,
                                 E, NB, NBLK, n_nodes);
    h2_kernel<<<(n_nodes + 3) / 4, 256, 0, stream>>>(x, W_eff, b_eff, dis, h2, pooled,
                                                     G * 64, n_nodes);
    gather_pool_kernel<<<(n_nodes + 3) / 4, 256, 0, stream>>>(payload, startv, cntv, dis,
                                                              (const __half2*)h2, b_gcn, batch,
                                                              pooled, n_nodes);
    final_kernel<<<G, 64, 0, stream>>>(pooled, fn_avg, inf_rate, W_fn1, b_fn1,
                                       W_fn2, b_fn2, W_bb1, b_bb1, W_out, b_out, logits);
}